// Round 16
// baseline (452.385 us; speedup 1.0000x reference)
//
#include <hip/hip_runtime.h>

#define BS 256
#define LD4(ptr) (*reinterpret_cast<const float4*>(ptr))

__device__ __forceinline__ float fast_acos(float x) {
    // Abramowitz & Stegun 4.4.45, branchless; |err| <= ~6.8e-5 rad.
    float ax = fabsf(x);
    float s  = sqrtf(fmaxf(0.f, 1.f - ax));
    float p  = fmaf(ax, fmaf(ax, fmaf(ax, -0.0187293f, 0.0742610f), -0.2121144f), 1.5707288f);
    float r  = s * p;
    return (x >= 0.f) ? r : 3.14159265358979f - r;
}

__device__ __forceinline__ float dir_item(float4 L, float4 O, float4 Tn, bool first) {
    float pa = L.x + O.x, pb = L.y + O.y, pc = L.z + O.z, pd = L.w + O.w;
    float Px0 = pa - 0.5f * pc, Py0 = pb - 0.5f * pd, Px1 = pa, Py1 = pb;
    float Tx0 = Tn.x - 0.5f * Tn.z, Ty0 = Tn.y - 0.5f * Tn.w, Tx1 = Tn.x, Ty1 = Tn.y;
    float Lx1 = L.x - 0.5f * L.z, Ly1 = L.y - 0.5f * L.w;
    float Lx0, Ly0;
    if (first) { Lx0 = Lx1; Ly0 = Ly1; Lx1 = L.x; Ly1 = L.y; }
    else       { Lx0 = 0.5f * (L.x - L.z); Ly0 = 0.5f * (L.y - L.w); }

    float lxs[5] = {0.5f * (Lx0 + Lx1), Lx0, Lx0, Lx1, Lx1};
    float lys[5] = {0.5f * (Ly0 + Ly1), Ly0, Ly1, Ly0, Ly1};
    float pxs[5] = {0.5f * (Px0 + Px1), Px0, Px0, Px1, Px1};
    float pys[5] = {0.5f * (Py0 + Py1), Py0, Py1, Py0, Py1};
    float txs[5] = {0.5f * (Tx0 + Tx1), Tx0, Tx0, Tx1, Tx1};
    float tys[5] = {0.5f * (Ty0 + Ty1), Ty0, Ty1, Ty0, Ty1};

    float acc = 0.f;
    #pragma unroll
    for (int k = 0; k < 5; ++k) {
        float pdx = pxs[k] - lxs[k], pdy = pys[k] - lys[k];
        float tdx = txs[k] - lxs[k], tdy = tys[k] - lys[k];
        float p2  = pdx * pdx + pdy * pdy;
        float t2  = tdx * tdx + tdy * tdy;
        float dot = pdx * tdx + pdy * tdy;
        float inv = rsqrtf(p2 * t2);   // ref's +1e-6 eps shifts cos by <=1e-5: within budget
        float cosang = fminf(1.0f, fmaxf(-1.0f, dot * inv));
        acc += fast_acos(cosang);
    }
    return acc;
}

__device__ __forceinline__ float sl1_4(float4 O, float4 D) {
    float s = 0.f;
    { float d = O.x - D.x, ad = fabsf(d); s += (ad < 1.f) ? 0.5f * d * d : ad - 0.5f; }
    { float d = O.y - D.y, ad = fabsf(d); s += (ad < 1.f) ? 0.5f * d * d : ad - 0.5f; }
    { float d = O.z - D.z, ad = fabsf(d); s += (ad < 1.f) ? 0.5f * d * d : ad - 0.5f; }
    { float d = O.w - D.w, ad = fabsf(d); s += (ad < 1.f) ? 0.5f * d * d : ad - 0.5f; }
    return s;
}

// Phase-1 work for one (p, t-quarter) unit: dir-loss contribution returned,
// smooth-L1*w for the 4 frames left in s[4] (written to out after the grid
// barrier, fused with the direction constant -> out is written exactly once).
__device__ __forceinline__ float do_unit(long long u, int P, float w,
                                         const float* __restrict__ outputs,
                                         const float* __restrict__ targets,
                                         float s[4], int& grp_out, long long& p_out) {
    int grp     = (int)(u / P);            // 0..3
    long long p = u - (long long)grp * P;
    grp_out = grp; p_out = p;
    const long long ts8 = 8ll * P, os4 = 4ll * P;
    const float* tb = targets + ((long long)(grp * 4) * P + p) * 8;
    const float* ob = outputs + ((long long)(grp * 4) * P + p) * 4;
    const bool has4 = (grp < 3);

    float4 Tf0 = LD4(tb);
    float4 Tf1 = LD4(tb + ts8);
    float4 Tf2 = LD4(tb + 2 * ts8);
    float4 Tf3 = LD4(tb + 3 * ts8);
    float4 Ts0 = LD4(tb + 4);
    float4 Ts1 = LD4(tb + ts8 + 4);
    float4 Ts2 = LD4(tb + 2 * ts8 + 4);
    float4 Ts3 = LD4(tb + 3 * ts8 + 4);
    float4 O0  = LD4(ob);
    float4 O1  = LD4(ob + os4);
    float4 O2  = LD4(ob + 2 * os4);
    float4 O3  = LD4(ob + 3 * os4);
    float4 Tf4 = has4 ? LD4(tb + 4 * ts8) : make_float4(0.f, 0.f, 0.f, 0.f);

    s[0] = sl1_4(O0, Ts0) * w;
    s[1] = sl1_4(O1, Ts1) * w;
    s[2] = sl1_4(O2, Ts2) * w;
    s[3] = sl1_4(O3, Ts3) * w;

    float acc = dir_item(Tf0, O0, Tf1, grp == 0);
    acc += dir_item(Tf1, O1, Tf2, false);
    acc += dir_item(Tf2, O2, Tf3, false);
    if (has4) acc += dir_item(Tf3, O3, Tf4, false);
    return acc;
}

// Single kernel: phase 1 (dir partials + sl1 in regs) -> software grid barrier
// (all G blocks co-resident: G=1563 <= 8 blocks/CU * 256 CU guaranteed by
// __launch_bounds__(256,8) => VGPR<=64) -> per-block partials reduction ->
// phase 2 (out = sl1*w + c, single write). Counter is zeroed per launch by
// hipMemsetAsync, so every call/replay is identical.
__global__ __launch_bounds__(BS, 8)
void fused_all(const float* __restrict__ outputs,
               const float* __restrict__ targets,
               float* __restrict__ out,
               float* __restrict__ partials,
               unsigned int* __restrict__ counter,
               int P, float w, int G) {
    __shared__ float  smem[BS / 64];
    __shared__ double dsm[BS / 64];
    __shared__ float  c_sh;
    const long long total = 4ll * P;
    const long long NT = (long long)G * BS;
    long long gid = (long long)blockIdx.x * BS + threadIdx.x;

    float s0[4], s1[4];
    int g0 = 0, g1 = 0;
    long long p0 = 0, p1 = 0;
    bool h0 = gid < total, h1 = (gid + NT) < total;

    float acc = 0.f;
    if (h0) acc += do_unit(gid, P, w, outputs, targets, s0, g0, p0);
    if (h1) acc += do_unit(gid + NT, P, w, outputs, targets, s1, g1, p1);

    // ---- block reduction of dir partial ----
    #pragma unroll
    for (int off = 32; off > 0; off >>= 1) acc += __shfl_down(acc, off, 64);
    int lane = threadIdx.x & 63, wv = threadIdx.x >> 6;
    if (lane == 0) smem[wv] = acc;
    __syncthreads();

    // ---- software grid barrier (agent-scope atomics, G16) ----
    if (threadIdx.x == 0) {
        float r = smem[0] + smem[1] + smem[2] + smem[3];
        __hip_atomic_store(&partials[blockIdx.x], r, __ATOMIC_RELEASE,
                           __HIP_MEMORY_SCOPE_AGENT);
        unsigned int done = __hip_atomic_fetch_add(counter, 1u, __ATOMIC_ACQ_REL,
                                                   __HIP_MEMORY_SCOPE_AGENT) + 1u;
        if (done < (unsigned int)G) {
            while (__hip_atomic_load(counter, __ATOMIC_ACQUIRE,
                                     __HIP_MEMORY_SCOPE_AGENT) < (unsigned int)G)
                __builtin_amdgcn_s_sleep(2);
        }
    }
    __syncthreads();

    // ---- every block reduces the G partials (L2/L3-resident, deterministic) ----
    double dacc = 0.0;
    for (int i = threadIdx.x; i < G; i += BS)
        dacc += (double)__hip_atomic_load(&partials[i], __ATOMIC_RELAXED,
                                          __HIP_MEMORY_SCOPE_AGENT);
    #pragma unroll
    for (int off = 32; off > 0; off >>= 1) dacc += __shfl_down(dacc, off, 64);
    if (lane == 0) dsm[wv] = dacc;
    __syncthreads();
    if (threadIdx.x == 0) {
        double tot = dsm[0] + dsm[1] + dsm[2] + dsm[3];
        c_sh = (float)(0.01 * 0.2 * tot / ((double)P * 15.0));
    }
    __syncthreads();
    float c = c_sh;

    // ---- phase 2: single fused write of out ----
    if (h0) {
        float* wb = out + (long long)(g0 * 4) * P + p0;
        wb[0] = s0[0] + c; wb[P] = s0[1] + c;
        wb[2ll * P] = s0[2] + c; wb[3ll * P] = s0[3] + c;
    }
    if (h1) {
        float* wb = out + (long long)(g1 * 4) * P + p1;
        wb[0] = s1[0] + c; wb[P] = s1[1] + c;
        wb[2ll * P] = s1[2] + c; wb[3ll * P] = s1[3] + c;
    }
}

extern "C" void kernel_launch(void* const* d_in, const int* in_sizes, int n_in,
                              void* d_out, int out_size, void* d_ws, size_t ws_size,
                              hipStream_t stream) {
    const float* outputs = (const float*)d_in[0];
    const float* targets = (const float*)d_in[1];
    float* out = (float*)d_out;
    float* partials = (float*)d_ws;                       // G floats
    unsigned int* counter = (unsigned int*)(partials + 2048);  // 8KB offset

    const int T = 16;
    int P = in_sizes[0] / (T * 4);                        // 200000

    long long units = 4ll * P;                            // 800,000
    int G = (int)((units + 2ll * BS - 1) / (2ll * BS));   // 1563 blocks (2 units/thread)

    hipMemsetAsync(counter, 0, sizeof(unsigned int), stream);
    fused_all<<<G, BS, 0, stream>>>(outputs, targets, out, partials, counter,
                                    P, 0.99f / (float)P, G);
}

// Round 17
// 46.515 us; speedup vs baseline: 9.7256x; 9.7256x over previous
//
#include <hip/hip_runtime.h>

#define BS 256
#define TILE 256

__device__ __forceinline__ int sw(int c) { return c ^ ((c >> 3) & 7); }

__device__ __forceinline__ void gload_lds16(const float* g, float* l) {
    __builtin_amdgcn_global_load_lds(
        (const __attribute__((address_space(1))) void*)g,
        (__attribute__((address_space(3))) void*)l, 16, 0, 0);
}

__device__ __forceinline__ float fast_acos(float x) {
    // Abramowitz & Stegun 4.4.45, branchless; |err| <= ~6.8e-5 rad.
    float ax = fabsf(x);
    float s  = sqrtf(fmaxf(0.f, 1.f - ax));
    float p  = fmaf(ax, fmaf(ax, fmaf(ax, -0.0187293f, 0.0742610f), -0.2121144f), 1.5707288f);
    float r  = s * p;
    return (x >= 0.f) ? r : 3.14159265358979f - r;
}

__device__ __forceinline__ float dir_item(float4 L, float4 O, float4 Tn, bool first) {
    float pa = L.x + O.x, pb = L.y + O.y, pc = L.z + O.z, pd = L.w + O.w;
    float Px0 = pa - 0.5f * pc, Py0 = pb - 0.5f * pd, Px1 = pa, Py1 = pb;
    float Tx0 = Tn.x - 0.5f * Tn.z, Ty0 = Tn.y - 0.5f * Tn.w, Tx1 = Tn.x, Ty1 = Tn.y;
    float Lx1 = L.x - 0.5f * L.z, Ly1 = L.y - 0.5f * L.w;
    float Lx0, Ly0;
    if (first) { Lx0 = Lx1; Ly0 = Ly1; Lx1 = L.x; Ly1 = L.y; }
    else       { Lx0 = 0.5f * (L.x - L.z); Ly0 = 0.5f * (L.y - L.w); }

    float lxs[5] = {0.5f * (Lx0 + Lx1), Lx0, Lx0, Lx1, Lx1};
    float lys[5] = {0.5f * (Ly0 + Ly1), Ly0, Ly1, Ly0, Ly1};
    float pxs[5] = {0.5f * (Px0 + Px1), Px0, Px0, Px1, Px1};
    float pys[5] = {0.5f * (Py0 + Py1), Py0, Py1, Py0, Py1};
    float txs[5] = {0.5f * (Tx0 + Tx1), Tx0, Tx0, Tx1, Tx1};
    float tys[5] = {0.5f * (Ty0 + Ty1), Ty0, Ty1, Ty0, Ty1};

    float acc = 0.f;
    #pragma unroll
    for (int k = 0; k < 5; ++k) {
        float pdx = pxs[k] - lxs[k], pdy = pys[k] - lys[k];
        float tdx = txs[k] - lxs[k], tdy = tys[k] - lys[k];
        float p2  = pdx * pdx + pdy * pdy;
        float t2  = tdx * tdx + tdy * tdy;
        float dot = pdx * tdx + pdy * tdy;
        float inv = rsqrtf(p2 * t2);   // ref's +1e-6 eps shifts cos by <=1e-5: within budget
        float cosang = fminf(1.0f, fmaxf(-1.0f, dot * inv));
        acc += fast_acos(cosang);
    }
    return acc;
}

__device__ __forceinline__ float sl1_4(float4 O, float4 D) {
    float s = 0.f;
    { float d = O.x - D.x, ad = fabsf(d); s += (ad < 1.f) ? 0.5f * d * d : ad - 0.5f; }
    { float d = O.y - D.y, ad = fabsf(d); s += (ad < 1.f) ? 0.5f * d * d : ad - 0.5f; }
    { float d = O.z - D.z, ad = fabsf(d); s += (ad < 1.f) ? 0.5f * d * d : ad - 0.5f; }
    { float d = O.w - D.w, ad = fabsf(d); s += (ad < 1.f) ? 0.5f * d * d : ad - 0.5f; }
    return s;
}

// Block = 256 p-records x one t-quarter. Stage 5 targets-rows (512 x 16B chunks
// each) + 4 outputs-rows (256 chunks) into LDS via global_load_lds (coalesced
// 1KB/wave DMA bursts, no VGPR round-trip). XOR swizzle s(c)=c^((c>>3)&7) is
// applied to the GLOBAL source chunk index (LDS dest stays linear, rule 21);
// compute reads chunk c at position s(c) -> ds_read_b128 is bank-balanced
// (8 lanes per 4-bank quad = conflict-free).
__global__ __launch_bounds__(BS, 2)
void fused_kernel(const float* __restrict__ outputs,
                  const float* __restrict__ targets,
                  float* __restrict__ out,
                  float* __restrict__ partials,
                  int P, int npb, float w) {
    __shared__ float lds[14336];      // 5*512 + 4*256 = 3584 chunks * 16B = 56KB
    __shared__ float smem[BS / 64];

    int g  = blockIdx.x / npb;                 // t-quarter 0..3
    int pb = blockIdx.x - g * npb;
    int p0 = pb * TILE;
    int Pv = P - p0; if (Pv > TILE) Pv = TILE; // valid records in this block
    const long long ts8 = 8ll * P, os4 = 4ll * P;
    const float* gT = targets + ((long long)(4 * g) * P + p0) * 8;
    const float* gO = outputs + ((long long)(4 * g) * P + p0) * 4;
    const int wv = threadIdx.x >> 6, lane = threadIdx.x & 63;
    const bool has4 = (g < 3);

    // ---- stage targets rows 0..3 (+4 if it exists): 2 issues/wave/row ----
    const int tcmax = 2 * Pv - 1;
    #pragma unroll
    for (int r = 0; r < 4; ++r) {
        #pragma unroll
        for (int k = 0; k < 2; ++k) {
            int q = wv * 128 + k * 64 + lane;          // linear LDS chunk pos
            int c = sw(q); if (c > tcmax) c = tcmax;   // swizzled, clamped source
            gload_lds16(gT + r * ts8 + c * 4, &lds[(r * 512 + q) * 4]);
        }
    }
    if (has4) {
        #pragma unroll
        for (int k = 0; k < 2; ++k) {
            int q = wv * 128 + k * 64 + lane;
            int c = sw(q); if (c > tcmax) c = tcmax;
            gload_lds16(gT + 4 * ts8 + c * 4, &lds[(4 * 512 + q) * 4]);
        }
    }
    // ---- stage outputs rows 0..3: 1 issue/wave/row ----
    const int ocmax = Pv - 1;
    #pragma unroll
    for (int r = 0; r < 4; ++r) {
        int q = wv * 64 + lane;
        int c = sw(q); if (c > ocmax) c = ocmax;
        gload_lds16(gO + r * os4 + c * 4, &lds[(2560 + r * 256 + q) * 4]);
    }
    asm volatile("s_waitcnt vmcnt(0)" ::: "memory");
    __syncthreads();

    // ---- compute from LDS ----
    float acc = 0.f;
    int i = threadIdx.x;
    if (i < Pv) {
        float4 Tf0 = *(float4*)&lds[(0 * 512 + sw(2 * i)) * 4];
        float4 Ts0 = *(float4*)&lds[(0 * 512 + sw(2 * i + 1)) * 4];
        float4 Tf1 = *(float4*)&lds[(1 * 512 + sw(2 * i)) * 4];
        float4 Ts1 = *(float4*)&lds[(1 * 512 + sw(2 * i + 1)) * 4];
        float4 Tf2 = *(float4*)&lds[(2 * 512 + sw(2 * i)) * 4];
        float4 Ts2 = *(float4*)&lds[(2 * 512 + sw(2 * i + 1)) * 4];
        float4 Tf3 = *(float4*)&lds[(3 * 512 + sw(2 * i)) * 4];
        float4 Ts3 = *(float4*)&lds[(3 * 512 + sw(2 * i + 1)) * 4];
        float4 O0  = *(float4*)&lds[(2560 + 0 * 256 + sw(i)) * 4];
        float4 O1  = *(float4*)&lds[(2560 + 1 * 256 + sw(i)) * 4];
        float4 O2  = *(float4*)&lds[(2560 + 2 * 256 + sw(i)) * 4];
        float4 O3  = *(float4*)&lds[(2560 + 3 * 256 + sw(i)) * 4];
        float4 Tf4 = has4 ? *(float4*)&lds[(4 * 512 + sw(2 * i)) * 4]
                          : make_float4(0.f, 0.f, 0.f, 0.f);

        float* wb = out + (long long)(4 * g) * P + p0 + i;
        wb[0]       = sl1_4(O0, Ts0) * w;
        wb[P]       = sl1_4(O1, Ts1) * w;
        wb[2ll * P] = sl1_4(O2, Ts2) * w;
        wb[3ll * P] = sl1_4(O3, Ts3) * w;

        acc  = dir_item(Tf0, O0, Tf1, g == 0);
        acc += dir_item(Tf1, O1, Tf2, false);
        acc += dir_item(Tf2, O2, Tf3, false);
        if (has4) acc += dir_item(Tf3, O3, Tf4, false);
    }

    #pragma unroll
    for (int off = 32; off > 0; off >>= 1) acc += __shfl_down(acc, off, 64);
    if (lane == 0) smem[wv] = acc;
    __syncthreads();
    if (threadIdx.x == 0)
        partials[blockIdx.x] = smem[0] + smem[1] + smem[2] + smem[3];
}

__global__ void finalize_kernel(const float* __restrict__ partials, int nb,
                                float* __restrict__ out, long long n4, int P) {
    __shared__ double dsm[BS / 64];
    __shared__ float c_sh;
    double dacc = 0.0;
    for (int i = threadIdx.x; i < nb; i += BS) dacc += (double)partials[i];
    #pragma unroll
    for (int off = 32; off > 0; off >>= 1) dacc += __shfl_down(dacc, off, 64);
    int lane = threadIdx.x & 63, w = threadIdx.x >> 6;
    if (lane == 0) dsm[w] = dacc;
    __syncthreads();
    if (threadIdx.x == 0) {
        double tot = dsm[0] + dsm[1] + dsm[2] + dsm[3];
        c_sh = (float)(0.01 * 0.2 * tot / ((double)P * 15.0));
    }
    __syncthreads();
    float c = c_sh;

    float4* o4 = reinterpret_cast<float4*>(out);
    long long stride = (long long)gridDim.x * blockDim.x;
    for (long long i = (long long)blockIdx.x * blockDim.x + threadIdx.x; i < n4; i += stride) {
        float4 v = o4[i];
        v.x += c; v.y += c; v.z += c; v.w += c;
        o4[i] = v;
    }
}

extern "C" void kernel_launch(void* const* d_in, const int* in_sizes, int n_in,
                              void* d_out, int out_size, void* d_ws, size_t ws_size,
                              hipStream_t stream) {
    const float* outputs = (const float*)d_in[0];
    const float* targets = (const float*)d_in[1];
    float* out = (float*)d_out;
    float* partials = (float*)d_ws;

    const int T = 16;
    int P = in_sizes[0] / (T * 4);             // 200000
    int npb = (P + TILE - 1) / TILE;           // 782 blocks per t-quarter
    int nb1 = 4 * npb;                         // 3128 blocks

    fused_kernel<<<nb1, BS, 0, stream>>>(outputs, targets, out, partials,
                                         P, npb, 0.99f / (float)P);

    long long n4 = (long long)out_size / 4;
    int nb2 = (int)((n4 + BS - 1) / BS);
    if (nb2 > 2048) nb2 = 2048;
    finalize_kernel<<<nb2, BS, 0, stream>>>(partials, nb1, out, n4, P);
}